// Round 5
// baseline (164.306 us; speedup 1.0000x reference)
//
#include <hip/hip_runtime.h>

// IF spiking neuron, T=3 timesteps fused.
// x: [3, 4, 2048, 4096] f32; out: [3, 4, 2048, 4096] f32.
// Streaming elementwise: m = 0.5*thr + x0+x1+x2; 3x {s=m>thr?thr:0; m-=s}.
// Non-temporal loads/stores (zero reuse), unroll-4 branch-free main loop
// (12 outstanding loads/thread) + generic tail (empty for this shape:
// n4 = 8,388,608 = 16 * 524,288 threads).
//
// R4 post-mortem: PROCESS declared a local `j` initialized from its own
// macro arg — calling PROCESS(j + stride) self-referenced the uninitialized
// inner `j` (UB). Macro local renamed to jj_ (hygiene).

typedef float f32x4 __attribute__((ext_vector_type(4)));

__global__ __launch_bounds__(256) void IF_80702435492066_kernel(
    const f32x4* __restrict__ x,
    const float* __restrict__ alpha_p,
    f32x4* __restrict__ out,
    long long n4)  // f32x4 elements per timestep plane
{
    const float thr = alpha_p[0];
    const float half_thr = 0.5f * thr;

    const long long stride = (long long)gridDim.x * blockDim.x;
    const long long idx = (long long)blockIdx.x * blockDim.x + threadIdx.x;

    #define PROCESS(J)                                                      \
        {                                                                   \
            const long long jj_ = (J);                                      \
            const f32x4 a = __builtin_nontemporal_load(&x[jj_]);            \
            const f32x4 b = __builtin_nontemporal_load(&x[jj_ + n4]);       \
            const f32x4 c = __builtin_nontemporal_load(&x[jj_ + 2 * n4]);   \
            f32x4 o0, o1, o2;                                               \
            _Pragma("unroll")                                               \
            for (int k = 0; k < 4; ++k) {                                   \
                float m = half_thr + ((a[k] + b[k]) + c[k]);                \
                float s0 = (m > thr) ? thr : 0.0f; m -= s0;                 \
                float s1 = (m > thr) ? thr : 0.0f; m -= s1;                 \
                float s2 = (m > thr) ? thr : 0.0f;                          \
                o0[k] = s0; o1[k] = s1; o2[k] = s2;                         \
            }                                                               \
            __builtin_nontemporal_store(o0, &out[jj_]);                     \
            __builtin_nontemporal_store(o1, &out[jj_ + n4]);                \
            __builtin_nontemporal_store(o2, &out[jj_ + 2 * n4]);            \
        }

    // Branch-free unroll-4 main loop over the exactly-divisible region.
    const long long nfull = (n4 / (4 * stride)) * (4 * stride);
    for (long long j = idx; j < nfull; j += 4 * stride) {
        PROCESS(j)
        PROCESS(j + stride)
        PROCESS(j + 2 * stride)
        PROCESS(j + 3 * stride)
    }
    // Generic tail (empty for the benched shape).
    for (long long j = nfull + idx; j < n4; j += stride) {
        PROCESS(j)
    }
    #undef PROCESS
}

extern "C" void kernel_launch(void* const* d_in, const int* in_sizes, int n_in,
                              void* d_out, int out_size, void* d_ws, size_t ws_size,
                              hipStream_t stream) {
    const float* x     = (const float*)d_in[0];
    const float* alpha = (const float*)d_in[1];
    float* out         = (float*)d_out;

    // in_sizes[0] = 3 * plane; plane = 4*2048*4096 = 33,554,432 (divisible by 4)
    const long long plane = (long long)in_sizes[0] / 3;
    const long long n4 = plane / 4;

    const int block = 256;
    const int grid = 2048;  // 8 blocks/CU (32 waves/CU); 4 unroll-4 iters/thread

    IF_80702435492066_kernel<<<grid, block, 0, stream>>>(
        (const f32x4*)x, alpha, (f32x4*)out, n4);
}

// Round 6
// 147.389 us; speedup vs baseline: 1.1148x; 1.1148x over previous
//
#include <hip/hip_runtime.h>

// IF spiking neuron, T=3 timesteps fused.
// x: [3, 4, 2048, 4096] f32; out: [3, 4, 2048, 4096] f32.
// Streaming elementwise: m = 0.5*thr + x0+x1+x2; 3x {s=m>thr?thr:0; m-=s}.
//
// R5 post-mortem: unroll-4 regressed (164 µs) vs unroll-2 (148 µs) — VGPR
// pressure from 12 live loads halves occupancy; BW-bound wants TLP not ILP.
// This round: keep the unroll-2 body but give every thread EXACTLY one body
// (grid = n4/2 threads, 16384 blocks): no loop, no branch, minimal VGPR,
// max occupancy. Non-temporal loads/stores throughout (zero reuse).

typedef float f32x4 __attribute__((ext_vector_type(4)));

__device__ __forceinline__ void process_one(
    const f32x4* __restrict__ x, f32x4* __restrict__ out,
    long long j, long long n4, float thr, float half_thr)
{
    const f32x4 a = __builtin_nontemporal_load(&x[j]);
    const f32x4 b = __builtin_nontemporal_load(&x[j + n4]);
    const f32x4 c = __builtin_nontemporal_load(&x[j + 2 * n4]);
    f32x4 o0, o1, o2;
    #pragma unroll
    for (int k = 0; k < 4; ++k) {
        float m = half_thr + ((a[k] + b[k]) + c[k]);
        float s0 = (m > thr) ? thr : 0.0f; m -= s0;
        float s1 = (m > thr) ? thr : 0.0f; m -= s1;
        float s2 = (m > thr) ? thr : 0.0f;
        o0[k] = s0; o1[k] = s1; o2[k] = s2;
    }
    __builtin_nontemporal_store(o0, &out[j]);
    __builtin_nontemporal_store(o1, &out[j + n4]);
    __builtin_nontemporal_store(o2, &out[j + 2 * n4]);
}

// Exact-cover path: each thread handles j = tid and j = tid + n4/2.
__global__ __launch_bounds__(256) void IF_80702435492066_exact(
    const f32x4* __restrict__ x,
    const float* __restrict__ alpha_p,
    f32x4* __restrict__ out,
    long long half_n4)  // n4 / 2
{
    const float thr = alpha_p[0];
    const float half_thr = 0.5f * thr;
    const long long n4 = 2 * half_n4;
    const long long tid = (long long)blockIdx.x * blockDim.x + threadIdx.x;
    process_one(x, out, tid, n4, thr, half_thr);
    process_one(x, out, tid + half_n4, n4, thr, half_thr);
}

// Generic fallback (any n4): grid-stride unroll-2 as in R3.
__global__ __launch_bounds__(256) void IF_80702435492066_generic(
    const f32x4* __restrict__ x,
    const float* __restrict__ alpha_p,
    f32x4* __restrict__ out,
    long long n4)
{
    const float thr = alpha_p[0];
    const float half_thr = 0.5f * thr;
    const long long stride = (long long)gridDim.x * blockDim.x;
    const long long idx = (long long)blockIdx.x * blockDim.x + threadIdx.x;
    for (long long j0 = idx; j0 < n4; j0 += 2 * stride) {
        process_one(x, out, j0, n4, thr, half_thr);
        const long long j1 = j0 + stride;
        if (j1 < n4) process_one(x, out, j1, n4, thr, half_thr);
    }
}

extern "C" void kernel_launch(void* const* d_in, const int* in_sizes, int n_in,
                              void* d_out, int out_size, void* d_ws, size_t ws_size,
                              hipStream_t stream) {
    const float* x     = (const float*)d_in[0];
    const float* alpha = (const float*)d_in[1];
    float* out         = (float*)d_out;

    // in_sizes[0] = 3 * plane; plane = 4*2048*4096 = 33,554,432
    const long long plane = (long long)in_sizes[0] / 3;
    const int block = 256;

    if (plane % 8 == 0) {
        const long long n4 = plane / 4;          // 8,388,608
        const long long half_n4 = n4 / 2;        // 4,194,304 threads
        const long long nblocks = half_n4 / block; // 16384 (divides exactly)
        if (nblocks * block == half_n4) {
            IF_80702435492066_exact<<<(int)nblocks, block, 0, stream>>>(
                (const f32x4*)x, alpha, (f32x4*)out, half_n4);
            return;
        }
    }
    // Fallback for odd shapes.
    const long long n4 = plane / 4;
    IF_80702435492066_generic<<<2048, block, 0, stream>>>(
        (const f32x4*)x, alpha, (f32x4*)out, n4);
}